// Round 2
// baseline (809.828 us; speedup 1.0000x reference)
//
#include <hip/hip_runtime.h>
#include <hip/hip_bf16.h>

#define B_ 4
#define S_ 4096
#define D_ 512
#define SCALE_Q 0.04419417382415922f   // 1/sqrt(512), folded into Q at stage 1

typedef __attribute__((ext_vector_type(8))) short short8;   // 8 x bf16 (4 VGPR) MFMA frag
typedef __attribute__((ext_vector_type(4))) float f32x4;

__device__ __forceinline__ unsigned short f2bf(float f) {
  unsigned u = __builtin_bit_cast(unsigned, f);
  u += 0x7fffu + ((u >> 16) & 1u);          // RNE
  return (unsigned short)(u >> 16);
}

// ---------------------------------------------------------------------------
// Prep: convert Wq/Wk/Wv fp32 [512][512] -> bf16 wb[3][512][512]
// 384 blocks x 256 threads, 8 elems/thread.
// ---------------------------------------------------------------------------
__global__ __launch_bounds__(256) void cvtw_kernel(
    const float* __restrict__ Wq, const float* __restrict__ Wk,
    const float* __restrict__ Wv, unsigned short* __restrict__ wb)
{
  const float* Ws[3] = {Wq, Wk, Wv};
  const int g   = blockIdx.x * 256 + threadIdx.x;  // 0..98303
  const int w   = g >> 15;                         // block-uniform (128 blocks/matrix)
  const int idx = (g & 32767) * 8;
  const float* src = Ws[w] + idx;
  float4 a = *reinterpret_cast<const float4*>(src);
  float4 b = *reinterpret_cast<const float4*>(src + 4);
  ushort4 h0, h1;
  h0.x = f2bf(a.x); h0.y = f2bf(a.y); h0.z = f2bf(a.z); h0.w = f2bf(a.w);
  h1.x = f2bf(b.x); h1.y = f2bf(b.y); h1.z = f2bf(b.z); h1.w = f2bf(b.w);
  unsigned short* dst = wb + ((size_t)w << 18) + idx;
  *reinterpret_cast<ushort4*>(dst)     = h0;
  *reinterpret_cast<ushort4*>(dst + 4) = h1;
}

// ---------------------------------------------------------------------------
// Stage 1: Q = relu(x Wq^T + bq) * 1/sqrt(D)   -> bf16 [B*S][D]
//          K = relu(x Wk^T + bk)               -> bf16 [B*S][D]
//          V = relu(x Wv^T + bv)               -> bf16 TRANSPOSED  Vt[b][d][s]
// Block: 64 x-rows, x staged once (fp32->bf16, 32 iters = full 64x512!).
// W staged per (ws,nt) from prepacked bf16 (pure uint4 copy, 16 iters).
// ---------------------------------------------------------------------------
__global__ __launch_bounds__(256, 1) void qkv_kernel(
    const float* __restrict__ x,
    const unsigned short* __restrict__ wb,
    const float* __restrict__ bq, const float* __restrict__ bk,
    const float* __restrict__ bv,
    unsigned short* __restrict__ qo, unsigned short* __restrict__ ko,
    unsigned short* __restrict__ vto)
{
  __shared__ unsigned short xl[64 * 520];   // 64 rows x 512 (+8 pad) bf16
  __shared__ unsigned short wl[64 * 520];

  const int tid  = threadIdx.x;
  const int lane = tid & 63;
  const int wv   = tid >> 6;
  const int m0   = blockIdx.x * 64;
  const int l15  = lane & 15;
  const int lg   = lane >> 4;

  // stage x tile: 64 x 512 fp32 -> bf16  (8192 float4 / 256 thr = 32 iters)
#pragma unroll
  for (int i = 0; i < 32; ++i) {
    int f   = tid + 256 * i;          // float4 index 0..8191
    int row = f >> 7;                 // 0..63
    int c4  = f & 127;                // 0..127
    float4 v = *reinterpret_cast<const float4*>(x + (size_t)(m0 + row) * D_ + c4 * 4);
    ushort4 h;
    h.x = f2bf(v.x); h.y = f2bf(v.y); h.z = f2bf(v.z); h.w = f2bf(v.w);
    *reinterpret_cast<ushort4*>(&xl[row * 520 + c4 * 4]) = h;
  }

  const float* bsel[3] = {bq, bk, bv};

#pragma unroll
  for (int ws = 0; ws < 3; ++ws) {
    for (int nt = 0; nt < 8; ++nt) {
      __syncthreads();                // prev readers of wl done (covers xl staging too)
      // stage W n-tile: 64 x 512 bf16 = 4096 uint4 / 256 thr = 16 iters
      const unsigned short* wsrc = wb + ((size_t)ws << 18) + (size_t)nt * 64 * D_;
#pragma unroll
      for (int i = 0; i < 16; ++i) {
        int f   = tid + 256 * i;      // uint4 index 0..4095
        int row = f >> 6;             // 0..63
        int c8  = f & 63;             // 0..63 (x8 elems)
        uint4 v = *reinterpret_cast<const uint4*>(wsrc + (size_t)row * D_ + c8 * 8);
        *reinterpret_cast<uint4*>(&wl[row * 520 + c8 * 8]) = v;
      }
      __syncthreads();

      f32x4 acc[4];
#pragma unroll
      for (int nf = 0; nf < 4; ++nf) acc[nf] = f32x4{0.f, 0.f, 0.f, 0.f};

      const int arow = wv * 16 + l15;
#pragma unroll
      for (int ks = 0; ks < 16; ++ks) {
        short8 a = *reinterpret_cast<const short8*>(&xl[arow * 520 + ks * 32 + lg * 8]);
#pragma unroll
        for (int nf = 0; nf < 4; ++nf) {
          short8 bb = *reinterpret_cast<const short8*>(&wl[(nf * 16 + l15) * 520 + ks * 32 + lg * 8]);
          acc[nf] = __builtin_amdgcn_mfma_f32_16x16x32_bf16(a, bb, acc[nf], 0, 0, 0);
        }
      }

      // epilogue: bias + relu (+scale for Q), store
#pragma unroll
      for (int nf = 0; nf < 4; ++nf) {
        const int col    = nt * 64 + nf * 16 + l15;
        const float bias = bsel[ws][col];
        const int rbase  = m0 + wv * 16 + lg * 4;   // C: row=(lane>>4)*4+reg
        if (ws == 2) {
          // V transposed: Vt[b][d][s], 4 consecutive s -> one 8B store
          const int bb = rbase >> 12;
          const int ss = rbase & 4095;
          ushort4 h;
          h.x = f2bf(fmaxf(acc[nf][0] + bias, 0.f));
          h.y = f2bf(fmaxf(acc[nf][1] + bias, 0.f));
          h.z = f2bf(fmaxf(acc[nf][2] + bias, 0.f));
          h.w = f2bf(fmaxf(acc[nf][3] + bias, 0.f));
          *reinterpret_cast<ushort4*>(vto + ((size_t)bb * D_ + col) * S_ + ss) = h;
        } else {
          unsigned short* o = (ws == 0) ? qo : ko;
          const float sc = (ws == 0) ? SCALE_Q : 1.0f;
#pragma unroll
          for (int r = 0; r < 4; ++r) {
            float v = fmaxf(acc[nf][r] + bias, 0.f) * sc;
            o[(size_t)(rbase + r) * D_ + col] = f2bf(v);
          }
        }
      }
    }
  }
}

// ---------------------------------------------------------------------------
// Stage 2: flash attention. Grid = 256 blocks (1/CU), block = 4 waves.
// Each wave owns 16 q-rows (Q frags in regs); KVBLK=32, K/V dbuf LDS with
// register prefetch; ONE __syncthreads per kv-tile (write targets cur^1,
// which nobody reads this iteration). Softmax fp32 online; P bounced via
// wave-private LDS (no barrier needed) to MFMA A layout.
// ---------------------------------------------------------------------------
__global__ __launch_bounds__(256, 1) void attn_kernel(
    const unsigned short* __restrict__ qb_,
    const unsigned short* __restrict__ kb_,
    const unsigned short* __restrict__ vb_,
    float* __restrict__ out)
{
  __shared__ unsigned short kl[2][32 * 520];   // K tile: 32 rows x 512 (+8 pad)
  __shared__ unsigned short vl[2][512 * 40];   // Vt tile: 512 d-rows x 32 (+8 pad)
  __shared__ unsigned short pl[4][16 * 40];    // wave-private P bounce: 16 x 32 (+8)

  const int tid  = threadIdx.x;
  const int lane = tid & 63;
  const int wv   = tid >> 6;
  const int l15  = lane & 15;
  const int lg   = lane >> 4;

  // XCD-aware decode: xcd=bid&7; each XCD pair serves one batch
  const int bid = blockIdx.x;
  const int xcd = bid & 7;
  const int bb  = xcd >> 1;
  const int qt  = (xcd & 1) * 32 + (bid >> 3);

  const unsigned short* qb = qb_ + (size_t)bb * S_ * D_;
  const unsigned short* kb = kb_ + (size_t)bb * S_ * D_;
  const unsigned short* vb = vb_ + (size_t)bb * D_ * S_;

  const int q0 = qt * 64 + wv * 16;

  // hoist Q fragments (16 rows x 512 -> 16 frags, 64 VGPR)
  short8 qf[16];
#pragma unroll
  for (int ks = 0; ks < 16; ++ks)
    qf[ks] = *reinterpret_cast<const short8*>(qb + (size_t)(q0 + l15) * D_ + ks * 32 + lg * 8);

  f32x4 o[32];
#pragma unroll
  for (int i = 0; i < 32; ++i) o[i] = f32x4{0.f, 0.f, 0.f, 0.f};
  float m[4], l[4];
#pragma unroll
  for (int r = 0; r < 4; ++r) { m[r] = -1e30f; l[r] = 0.f; }

  uint4 kreg[8], vreg[8];

  auto loadK = [&](int kt) {
#pragma unroll
    for (int i = 0; i < 8; ++i) {
      int row = tid >> 3, c = (tid & 7) + 8 * i;
      kreg[i] = *reinterpret_cast<const uint4*>(kb + (size_t)(kt * 32 + row) * D_ + c * 8);
    }
  };
  auto loadV = [&](int kt) {
#pragma unroll
    for (int i = 0; i < 8; ++i) {
      int d = (tid >> 2) + 64 * i, c = tid & 3;
      vreg[i] = *reinterpret_cast<const uint4*>(vb + (size_t)d * S_ + kt * 32 + c * 8);
    }
  };
  auto writeK = [&](int buf) {
#pragma unroll
    for (int i = 0; i < 8; ++i) {
      int row = tid >> 3, c = (tid & 7) + 8 * i;
      *reinterpret_cast<uint4*>(&kl[buf][row * 520 + c * 8]) = kreg[i];
    }
  };
  auto writeV = [&](int buf) {
#pragma unroll
    for (int i = 0; i < 8; ++i) {
      int d = (tid >> 2) + 64 * i, c = tid & 3;
      *reinterpret_cast<uint4*>(&vl[buf][d * 40 + c * 8]) = vreg[i];
    }
  };

  // prologue: stage tile 0
  loadK(0); loadV(0);
  writeK(0); writeV(0);
  __syncthreads();

  int cur = 0;
  const int NT = S_ / 32;
  for (int kt = 0; kt < NT; ++kt) {
    if (kt + 1 < NT) { loadK(kt + 1); loadV(kt + 1); }   // global -> regs, flies over compute

    // ---- QK^T: 16 q-rows x 32 kv (scale pre-folded into Q) ----
    f32x4 s[2];
    s[0] = f32x4{0.f, 0.f, 0.f, 0.f};
    s[1] = f32x4{0.f, 0.f, 0.f, 0.f};
#pragma unroll
    for (int ks = 0; ks < 16; ++ks) {
#pragma unroll
      for (int f = 0; f < 2; ++f) {
        short8 kf = *reinterpret_cast<const short8*>(&kl[cur][(f * 16 + l15) * 520 + ks * 32 + lg * 8]);
        s[f] = __builtin_amdgcn_mfma_f32_16x16x32_bf16(qf[ks], kf, s[f], 0, 0, 0);
      }
    }

    // ---- online softmax (C layout: row = lg*4+r, col = l15 + 16f) ----
    float rmax[4];
#pragma unroll
    for (int r = 0; r < 4; ++r) rmax[r] = fmaxf(s[0][r], s[1][r]);
#pragma unroll
    for (int msk = 1; msk < 16; msk <<= 1) {
#pragma unroll
      for (int r = 0; r < 4; ++r) rmax[r] = fmaxf(rmax[r], __shfl_xor(rmax[r], msk, 64));
    }

    float fac[4], rsum[4];
    f32x4 p[2];
#pragma unroll
    for (int r = 0; r < 4; ++r) {
      float mn = fmaxf(m[r], rmax[r]);
      fac[r] = __expf(m[r] - mn);
      m[r]   = mn;
      p[0][r] = __expf(s[0][r] - mn);
      p[1][r] = __expf(s[1][r] - mn);
      rsum[r] = p[0][r] + p[1][r];
    }
#pragma unroll
    for (int msk = 1; msk < 16; msk <<= 1) {
#pragma unroll
      for (int r = 0; r < 4; ++r) rsum[r] += __shfl_xor(rsum[r], msk, 64);
    }
#pragma unroll
    for (int r = 0; r < 4; ++r) l[r] = l[r] * fac[r] + rsum[r];

    // rescale O
#pragma unroll
    for (int i = 0; i < 32; ++i) {
#pragma unroll
      for (int r = 0; r < 4; ++r) o[i][r] *= fac[r];
    }

    // ---- P -> wave-private LDS (bf16), re-read in MFMA A layout ----
#pragma unroll
    for (int f = 0; f < 2; ++f) {
#pragma unroll
      for (int r = 0; r < 4; ++r)
        pl[wv][(lg * 4 + r) * 40 + f * 16 + l15] = f2bf(p[f][r]);
    }
    short8 pa = *reinterpret_cast<const short8*>(&pl[wv][l15 * 40 + lg * 8]);

    // ---- PV: O[16 x 512] += P[16 x 32] * V[32 x 512] ----
#pragma unroll
    for (int n = 0; n < 32; ++n) {
      short8 vf = *reinterpret_cast<const short8*>(&vl[cur][(n * 16 + l15) * 40 + lg * 8]);
      o[n] = __builtin_amdgcn_mfma_f32_16x16x32_bf16(pa, vf, o[n], 0, 0, 0);
    }

    // stage next tile into the buffer nobody reads this iteration
    if (kt + 1 < NT) {
      writeK(cur ^ 1);
      writeV(cur ^ 1);
    }
    __syncthreads();                 // staged tile visible; readers of cur done
    cur ^= 1;
  }

  // epilogue: normalize, store fp32
  float inv[4];
#pragma unroll
  for (int r = 0; r < 4; ++r) inv[r] = 1.0f / l[r];
  float* ob = out + (size_t)bb * S_ * D_;
#pragma unroll
  for (int n = 0; n < 32; ++n) {
#pragma unroll
    for (int r = 0; r < 4; ++r)
      ob[(size_t)(q0 + lg * 4 + r) * D_ + n * 16 + l15] = o[n][r] * inv[r];
  }
}

// ---------------------------------------------------------------------------
extern "C" void kernel_launch(void* const* d_in, const int* in_sizes, int n_in,
                              void* d_out, int out_size, void* d_ws, size_t ws_size,
                              hipStream_t stream) {
  const float* x  = (const float*)d_in[0];
  const float* Wq = (const float*)d_in[1];
  const float* bq = (const float*)d_in[2];
  const float* Wk = (const float*)d_in[3];
  const float* bk = (const float*)d_in[4];
  const float* Wv = (const float*)d_in[5];
  const float* bv = (const float*)d_in[6];
  float* out = (float*)d_out;

  // workspace: Q bf16 | K bf16 | Vt bf16 | Wbf16[3][512][512]  (~49.5 MiB)
  unsigned short* q  = (unsigned short*)d_ws;
  unsigned short* k  = q  + (size_t)B_ * S_ * D_;
  unsigned short* vt = k  + (size_t)B_ * S_ * D_;
  unsigned short* wb = vt + (size_t)B_ * S_ * D_;

  cvtw_kernel<<<384, 256, 0, stream>>>(Wq, Wk, Wv, wb);
  qkv_kernel<<<256, 256, 0, stream>>>(x, wb, bq, bk, bv, q, k, vt);
  attn_kernel<<<256, 256, 0, stream>>>(q, k, vt, out);
}

// Round 3
// 484.287 us; speedup vs baseline: 1.6722x; 1.6722x over previous
//
#include <hip/hip_runtime.h>
#include <hip/hip_bf16.h>

#define B_ 4
#define S_ 4096
#define D_ 512
#define SCALE_Q 0.04419417382415922f   // 1/sqrt(512), folded into Q at stage 1

typedef __attribute__((ext_vector_type(8))) short short8;   // 8 x bf16 (4 VGPR) MFMA frag
typedef __attribute__((ext_vector_type(4))) float f32x4;

__device__ __forceinline__ unsigned short f2bf(float f) {
  unsigned u = __builtin_bit_cast(unsigned, f);
  u += 0x7fffu + ((u >> 16) & 1u);          // RNE
  return (unsigned short)(u >> 16);
}

// ---------------------------------------------------------------------------
// Prep: convert Wq/Wk/Wv fp32 [512][512] -> bf16 wb[3][512][512]
// ---------------------------------------------------------------------------
__global__ __launch_bounds__(256) void cvtw_kernel(
    const float* __restrict__ Wq, const float* __restrict__ Wk,
    const float* __restrict__ Wv, unsigned short* __restrict__ wb)
{
  const float* Ws[3] = {Wq, Wk, Wv};
  const int g   = blockIdx.x * 256 + threadIdx.x;  // 0..98303
  const int w   = g >> 15;                         // block-uniform
  const int idx = (g & 32767) * 8;
  const float* src = Ws[w] + idx;
  float4 a = *reinterpret_cast<const float4*>(src);
  float4 b = *reinterpret_cast<const float4*>(src + 4);
  ushort4 h0, h1;
  h0.x = f2bf(a.x); h0.y = f2bf(a.y); h0.z = f2bf(a.z); h0.w = f2bf(a.w);
  h1.x = f2bf(b.x); h1.y = f2bf(b.y); h1.z = f2bf(b.z); h1.w = f2bf(b.w);
  unsigned short* dst = wb + ((size_t)w << 18) + idx;
  *reinterpret_cast<ushort4*>(dst)     = h0;
  *reinterpret_cast<ushort4*>(dst + 4) = h1;
}

// ---------------------------------------------------------------------------
// Stage 1 (512 thr, 8 waves = 2/SIMD): Q,K,V projections.
//   Q: row-major bf16 [B*S][D], pre-scaled by 1/sqrt(D)
//   K: PACKED fragment-major: kp[b][kt][ks*2+f][lane][8]
//        = K[kt*32 + f*16 + (lane&15)][ks*32 + (lane>>4)*8 + j]
//   V: PACKED fragment-major: vp[b][kt][n][lane][8]
//        = V[s = kt*32 + (lane>>4)*8 + j][d = n*16 + (lane&15)]  (transposed)
// Packed layouts make attn's global_load_lds (lane x 16B linear) land
// fragments exactly where ds_read_b128 wants them -> zero bank conflicts.
// ---------------------------------------------------------------------------
__global__ __launch_bounds__(512, 2) void qkv_kernel(
    const float* __restrict__ x,
    const unsigned short* __restrict__ wb,
    const float* __restrict__ bq, const float* __restrict__ bk,
    const float* __restrict__ bv,
    unsigned short* __restrict__ qo, unsigned short* __restrict__ kpk,
    unsigned short* __restrict__ vpk)
{
  __shared__ unsigned short xl[64 * 520];   // 64 rows x 512 (+8 pad) bf16
  __shared__ unsigned short wls[64 * 520];

  const int tid  = threadIdx.x;
  const int lane = tid & 63;
  const int wv   = tid >> 6;      // 0..7
  const int wr   = wv & 3;        // row group (16 rows)
  const int wc   = wv >> 2;       // col half (2 nf each)
  const int m0   = blockIdx.x * 64;
  const int l15  = lane & 15;
  const int lg   = lane >> 4;

  // stage x tile: 8192 float4 / 512 thr = 16 iters
#pragma unroll
  for (int i = 0; i < 16; ++i) {
    int f   = tid + 512 * i;
    int row = f >> 7;
    int c4  = f & 127;
    float4 v = *reinterpret_cast<const float4*>(x + (size_t)(m0 + row) * D_ + c4 * 4);
    ushort4 h;
    h.x = f2bf(v.x); h.y = f2bf(v.y); h.z = f2bf(v.z); h.w = f2bf(v.w);
    *reinterpret_cast<ushort4*>(&xl[row * 520 + c4 * 4]) = h;
  }

  const float* bsel[3] = {bq, bk, bv};

#pragma unroll
  for (int ws = 0; ws < 3; ++ws) {
    for (int nt = 0; nt < 8; ++nt) {
      __syncthreads();
      // stage W n-tile: 4096 uint4 / 512 thr = 8 iters
      const unsigned short* wsrc = wb + ((size_t)ws << 18) + (size_t)nt * 64 * D_;
#pragma unroll
      for (int i = 0; i < 8; ++i) {
        int f   = tid + 512 * i;
        int row = f >> 6;
        int c8  = f & 63;
        uint4 v = *reinterpret_cast<const uint4*>(wsrc + (size_t)row * D_ + c8 * 8);
        *reinterpret_cast<uint4*>(&wls[row * 520 + c8 * 8]) = v;
      }
      __syncthreads();

      f32x4 acc[2];
      acc[0] = f32x4{0.f, 0.f, 0.f, 0.f};
      acc[1] = f32x4{0.f, 0.f, 0.f, 0.f};

      const int arow = wr * 16 + l15;
#pragma unroll
      for (int ks = 0; ks < 16; ++ks) {
        short8 a = *reinterpret_cast<const short8*>(&xl[arow * 520 + ks * 32 + lg * 8]);
#pragma unroll
        for (int c = 0; c < 2; ++c) {
          int nfi = wc * 2 + c;
          short8 bb = *reinterpret_cast<const short8*>(&wls[(nfi * 16 + l15) * 520 + ks * 32 + lg * 8]);
          acc[c] = __builtin_amdgcn_mfma_f32_16x16x32_bf16(a, bb, acc[c], 0, 0, 0);
        }
      }

#pragma unroll
      for (int c = 0; c < 2; ++c) {
        const int col    = nt * 64 + (wc * 2 + c) * 16 + l15;
        const float bias = bsel[ws][col];
        const int rbase  = m0 + wr * 16 + lg * 4;   // token rows rbase..rbase+3
        const int bbb    = rbase >> 12;
        const int s      = rbase & 4095;
        if (ws == 2) {
          // packed V: off = (s>>5)*16384 + (col>>4)*512 + (((s>>3)&3)*16+(col&15))*8 + (s&7)
          unsigned short* vdst = vpk + (size_t)bbb * (S_ * D_);
          size_t off = (size_t)(s >> 5) * 16384 + (size_t)(col >> 4) * 512
                     + (((s >> 3) & 3) * 16 + (col & 15)) * 8 + (s & 7);
          ushort4 h;
          h.x = f2bf(fmaxf(acc[c][0] + bias, 0.f));
          h.y = f2bf(fmaxf(acc[c][1] + bias, 0.f));
          h.z = f2bf(fmaxf(acc[c][2] + bias, 0.f));
          h.w = f2bf(fmaxf(acc[c][3] + bias, 0.f));
          *reinterpret_cast<ushort4*>(vdst + off) = h;
        } else if (ws == 1) {
          // packed K: off = (s>>5)*16384 + ((col>>5)*2+((s>>4)&1))*512
          //                + (((col>>3)&3)*16+(s&15))*8 + (col&7)
          unsigned short* kdst = kpk + (size_t)bbb * (S_ * D_);
          size_t off = (size_t)(s >> 5) * 16384
                     + (size_t)((col >> 5) * 2 + ((s >> 4) & 1)) * 512
                     + (((col >> 3) & 3) * 16 + (s & 15)) * 8 + (col & 7);
#pragma unroll
          for (int r = 0; r < 4; ++r)
            kdst[off + r * 8] = f2bf(fmaxf(acc[c][r] + bias, 0.f));
        } else {
          // Q row-major, pre-scaled
#pragma unroll
          for (int r = 0; r < 4; ++r) {
            float v = fmaxf(acc[c][r] + bias, 0.f) * SCALE_Q;
            qo[(size_t)(rbase + r) * D_ + col] = f2bf(v);
          }
        }
      }
    }
  }
}

// ---------------------------------------------------------------------------
// Stage 2: flash attention, 256 blocks x 512 thr (8 waves = 2/SIMD).
// Anti-phase groups: waves 0-3 = kv tiles 0..63, waves 4-7 = 64..127, same
// 64 q-rows. Each group: single-buffered K/V (64KB) staged by
// global_load_lds from packed layouts (zero staging regs, zero conflicts).
// While group A computes, group B's loads fly (and vice versa). Final
// (m,l,O) merge through LDS. Defer-max rescale (THR=8).
// ---------------------------------------------------------------------------
__global__ __launch_bounds__(512, 2) void attn_kernel(
    const unsigned short* __restrict__ qb_,
    const unsigned short* __restrict__ kp_,
    const unsigned short* __restrict__ vp_,
    float* __restrict__ out)
{
  __shared__ unsigned short kvb[2][32768];   // per group: [0,16K) K frags, [16K,32K) V frags
  __shared__ unsigned short pl[8][640];      // wave-private P bounce 16x(32+8)

  const int tid  = threadIdx.x;
  const int lane = tid & 63;
  const int wv   = tid >> 6;     // 0..7
  const int g    = wv >> 2;      // kv-half group
  const int wl   = wv & 3;       // wave-in-group -> q-row group
  const int l15  = lane & 15;
  const int lg   = lane >> 4;

  const int bid = blockIdx.x;
  const int xcd = bid & 7;
  const int bb  = xcd >> 1;
  const int qt  = (xcd & 1) * 32 + (bid >> 3);

  const unsigned short* qb = qb_ + (size_t)bb * S_ * D_;
  const unsigned short* kp = kp_ + (size_t)bb * (S_ * D_);
  const unsigned short* vp = vp_ + (size_t)bb * (S_ * D_);

  const int q0 = qt * 64 + wl * 16;

  // Q fragments in regs (16 rows x 512 -> 16 frags, 64 VGPR)
  short8 qf[16];
#pragma unroll
  for (int ks = 0; ks < 16; ++ks)
    qf[ks] = *reinterpret_cast<const short8*>(qb + (size_t)(q0 + l15) * D_ + ks * 32 + lg * 8);

  f32x4 o[32];
#pragma unroll
  for (int i = 0; i < 32; ++i) o[i] = f32x4{0.f, 0.f, 0.f, 0.f};
  float m[4], l[4];
#pragma unroll
  for (int r = 0; r < 4; ++r) { m[r] = -1e30f; l[r] = 0.f; }

  unsigned short* myk = &kvb[g][0];
  unsigned short* myv = &kvb[g][16384];

  auto stage = [&](int kt) {
    const unsigned short* ksrc = kp + (size_t)kt * 16384;
    const unsigned short* vsrc = vp + (size_t)kt * 16384;
#pragma unroll
    for (int i = 0; i < 8; ++i) {
      int inst = wl * 8 + i;
      __builtin_amdgcn_global_load_lds(
          (const __attribute__((address_space(1))) void*)(ksrc + inst * 512 + lane * 8),
          (__attribute__((address_space(3))) void*)(myk + inst * 512), 16, 0, 0);
      __builtin_amdgcn_global_load_lds(
          (const __attribute__((address_space(1))) void*)(vsrc + inst * 512 + lane * 8),
          (__attribute__((address_space(3))) void*)(myv + inst * 512), 16, 0, 0);
    }
    asm volatile("s_waitcnt vmcnt(0)" ::: "memory");
  };

  auto compute = [&]() {
    // ---- QK^T (scale pre-folded into Q) ----
    f32x4 s0 = f32x4{0.f, 0.f, 0.f, 0.f};
    f32x4 s1 = f32x4{0.f, 0.f, 0.f, 0.f};
#pragma unroll
    for (int ks = 0; ks < 16; ++ks) {
      short8 k0 = *reinterpret_cast<const short8*>(myk + (ks * 2 + 0) * 512 + lane * 8);
      short8 k1 = *reinterpret_cast<const short8*>(myk + (ks * 2 + 1) * 512 + lane * 8);
      s0 = __builtin_amdgcn_mfma_f32_16x16x32_bf16(qf[ks], k0, s0, 0, 0, 0);
      s1 = __builtin_amdgcn_mfma_f32_16x16x32_bf16(qf[ks], k1, s1, 0, 0, 0);
    }

    // ---- online softmax (rows lg*4+r, cols l15 / 16+l15) ----
    float rmax[4];
#pragma unroll
    for (int r = 0; r < 4; ++r) rmax[r] = fmaxf(s0[r], s1[r]);
#pragma unroll
    for (int msk = 1; msk < 16; msk <<= 1) {
#pragma unroll
      for (int r = 0; r < 4; ++r) rmax[r] = fmaxf(rmax[r], __shfl_xor(rmax[r], msk, 64));
    }

    // defer-max: only rescale when tile max grew by > 8
    bool grow = (rmax[0] > m[0] + 8.f) || (rmax[1] > m[1] + 8.f) ||
                (rmax[2] > m[2] + 8.f) || (rmax[3] > m[3] + 8.f);
    if (__any((int)grow)) {
      float fa[4];
#pragma unroll
      for (int r = 0; r < 4; ++r) {
        float nm = fmaxf(m[r], rmax[r]);
        fa[r] = __expf(m[r] - nm);
        m[r] = nm;
        l[r] *= fa[r];
      }
#pragma unroll
      for (int i = 0; i < 32; ++i) {
#pragma unroll
        for (int r = 0; r < 4; ++r) o[i][r] *= fa[r];
      }
    }

    float rsum[4];
    f32x4 p0, p1;
#pragma unroll
    for (int r = 0; r < 4; ++r) {
      p0[r] = __expf(s0[r] - m[r]);
      p1[r] = __expf(s1[r] - m[r]);
      rsum[r] = p0[r] + p1[r];
    }
#pragma unroll
    for (int msk = 1; msk < 16; msk <<= 1) {
#pragma unroll
      for (int r = 0; r < 4; ++r) rsum[r] += __shfl_xor(rsum[r], msk, 64);
    }
#pragma unroll
    for (int r = 0; r < 4; ++r) l[r] += rsum[r];

    // ---- P -> wave-private LDS bounce to MFMA A layout ----
#pragma unroll
    for (int r = 0; r < 4; ++r) {
      pl[wv][(lg * 4 + r) * 40 + l15]      = f2bf(p0[r]);
      pl[wv][(lg * 4 + r) * 40 + 16 + l15] = f2bf(p1[r]);
    }
    short8 pa = *reinterpret_cast<const short8*>(&pl[wv][l15 * 40 + lg * 8]);

    // ---- PV: O[16x512] += P[16x32] * V[32x512] ----
#pragma unroll
    for (int n = 0; n < 32; ++n) {
      short8 vf = *reinterpret_cast<const short8*>(myv + n * 512 + lane * 8);
      o[n] = __builtin_amdgcn_mfma_f32_16x16x32_bf16(pa, vf, o[n], 0, 0, 0);
    }
  };

  // ---- anti-phase main loop ----
  if (g == 0) stage(0);
  __syncthreads();
  for (int w = 0; w < 64; ++w) {
    if (g == 0) compute(); else stage(64 + w);
    __syncthreads();
    if (g == 1) compute(); else if (w + 1 < 64) stage(w + 1);
    __syncthreads();
  }

  // ---- merge group partials (flash-decoding style) ----
  float* mrg = reinterpret_cast<float*>(&kvb[0][0]);   // 128 KB = 4 waves x 32 KB
  float* mls = reinterpret_cast<float*>(&pl[0][0]);    // m,l bounce
  if (g == 1) {
#pragma unroll
    for (int n = 0; n < 32; ++n)
      *reinterpret_cast<f32x4*>(mrg + wl * 8192 + (n * 64 + lane) * 4) = o[n];
#pragma unroll
    for (int r = 0; r < 4; ++r) {
      mls[wl * 512 + lane * 8 + r]     = m[r];
      mls[wl * 512 + lane * 8 + 4 + r] = l[r];
    }
  }
  __syncthreads();
  if (g == 0) {
    float fA[4], fB[4], inv[4];
#pragma unroll
    for (int r = 0; r < 4; ++r) {
      float mB = mls[wl * 512 + lane * 8 + r];
      float lB = mls[wl * 512 + lane * 8 + 4 + r];
      float mo = fmaxf(m[r], mB);
      fA[r] = __expf(m[r] - mo);
      fB[r] = __expf(mB - mo);
      inv[r] = 1.0f / (l[r] * fA[r] + lB * fB[r]);
    }
    float* ob = out + (size_t)bb * S_ * D_;
#pragma unroll
    for (int n = 0; n < 32; ++n) {
      f32x4 oB = *reinterpret_cast<const f32x4*>(mrg + wl * 8192 + (n * 64 + lane) * 4);
#pragma unroll
      for (int r = 0; r < 4; ++r)
        ob[(size_t)(q0 + lg * 4 + r) * D_ + n * 16 + l15] =
            (o[n][r] * fA[r] + oB[r] * fB[r]) * inv[r];
    }
  }
}

// ---------------------------------------------------------------------------
extern "C" void kernel_launch(void* const* d_in, const int* in_sizes, int n_in,
                              void* d_out, int out_size, void* d_ws, size_t ws_size,
                              hipStream_t stream) {
  const float* x  = (const float*)d_in[0];
  const float* Wq = (const float*)d_in[1];
  const float* bq = (const float*)d_in[2];
  const float* Wk = (const float*)d_in[3];
  const float* bk = (const float*)d_in[4];
  const float* Wv = (const float*)d_in[5];
  const float* bv = (const float*)d_in[6];
  float* out = (float*)d_out;

  // workspace: Q bf16 | K packed | V packed | Wbf16  (~49.5 MiB)
  unsigned short* q  = (unsigned short*)d_ws;
  unsigned short* kp = q  + (size_t)B_ * S_ * D_;
  unsigned short* vp = kp + (size_t)B_ * S_ * D_;
  unsigned short* wb = vp + (size_t)B_ * S_ * D_;

  cvtw_kernel<<<384, 256, 0, stream>>>(Wq, Wk, Wv, wb);
  qkv_kernel<<<256, 512, 0, stream>>>(x, wb, bq, bk, bv, q, kp, vp);
  attn_kernel<<<256, 512, 0, stream>>>(q, kp, vp, out);
}